// Round 2
// 79.914 us; speedup vs baseline: 1.0201x; 1.0201x over previous
//
#include <hip/hip_runtime.h>
#include <hip/hip_bf16.h>

// out[b, c, m] = weight[idx[b, m], c]   b<256, c<1024, m<64  (fp32, 64 MiB out)
//
// Per-block 64x64 (m x c) LDS transpose:
//  - block = (batch b, 64-channel tile c0). grid = 256*16 = 4096.
//  - Load: quarter-wave (16 lanes) reads one gathered row's 256B contiguous
//    (float4) -> full cacheline utilization.
//  - LDS tile stored transposed [cc][m], PAD=65: both scalar phases are
//    2 lanes/bank = conflict-free (m136).
//  - Store: 16 KiB fully contiguous per block, float4 per lane,
//    NON-TEMPORAL: the 64 MiB output stream must not evict the 4 MiB
//    weight table from the per-XCD 4 MiB L2s (write-stream thrashing is
//    the theory for the ~1.8 TB/s effective write BW). nt stores keep
//    weight L2-resident so gathers hit L2 (~34.5 TB/s) while the output
//    streams to HBM.
//  - NOTE: __builtin_nontemporal_store requires a NATIVE vector type;
//    HIP's float4 (HIP_vector_type class) is rejected -> use
//    ext_vector_type(4) for the store.

#define BS   256
#define M    64
#define C    1024
#define PAD  65   // 65 % 32 == 1 -> bank stride 1 for both access phases

typedef float fx4 __attribute__((ext_vector_type(4)));

__global__ __launch_bounds__(256) void gather_transpose_kernel(
    const int* __restrict__ idx,      // [BS*M] int32
    const float* __restrict__ w,      // [NUM_EMB, C] fp32
    float* __restrict__ out)          // [BS, C, 8, 8] fp32
{
    const int b  = blockIdx.x >> 4;          // 16 channel-tiles per batch
    const int c0 = (blockIdx.x & 15) << 6;   // 64 channels per block

    __shared__ int   s_idx[M];
    __shared__ float tile[M * PAD];          // [cc][m], transposed

    const int t = threadIdx.x;
    if (t < M) s_idx[t] = idx[b * M + t];
    __syncthreads();

    // ---- load phase: gather rows, coalesced 256B per 16-lane group ----
    const int f = t & 15;                    // float4 index within the 64-ch slice
#pragma unroll
    for (int j = 0; j < 4; ++j) {
        const int m   = (t >> 4) + (j << 4); // token 0..63
        const int row = s_idx[m];
        const fx4 v = *(const fx4*)(w + row * C + c0 + (f << 2));
        tile[((f << 2) + 0) * PAD + m] = v.x;
        tile[((f << 2) + 1) * PAD + m] = v.y;
        tile[((f << 2) + 2) * PAD + m] = v.z;
        tile[((f << 2) + 3) * PAD + m] = v.w;
    }
    __syncthreads();

    // ---- store phase: 16 KiB contiguous per block, nt float4 ----
    float* obase = out + (((size_t)(b * C + c0)) << 6);
#pragma unroll
    for (int j = 0; j < 4; ++j) {
        const int fo = (j << 8) + t;         // float4 slot 0..1023
        const int cc = fo >> 4;              // channel within tile
        const int m  = (fo & 15) << 2;       // token group of 4
        fx4 v;
        v.x = tile[cc * PAD + m + 0];
        v.y = tile[cc * PAD + m + 1];
        v.z = tile[cc * PAD + m + 2];
        v.w = tile[cc * PAD + m + 3];
        __builtin_nontemporal_store(v, (fx4*)(obase + (cc << 6) + m));
    }
}

extern "C" void kernel_launch(void* const* d_in, const int* in_sizes, int n_in,
                              void* d_out, int out_size, void* d_ws, size_t ws_size,
                              hipStream_t stream) {
    const int*   idx = (const int*)d_in[0];    // encoding_indices [256, 64]
    const float* w   = (const float*)d_in[1];  // weight [1024, 1024]
    float*       out = (float*)d_out;          // [256, 1024, 8, 8]

    dim3 grid(BS * (C / 64));  // 4096 blocks
    dim3 block(256);
    gather_transpose_kernel<<<grid, block, 0, stream>>>(idx, w, out);
}